// Round 2
// baseline (23.534 us; speedup 1.0000x reference)
//
#include <hip/hip_runtime.h>

// DictPlenoxels forward, sigma-only.
// Shapes: rays_o/rays_d (1024,3) f32; grid (32,32,32,32) f32; atoms (2,2,2,32,13) f32.
// Output: (1024, 219) f32.  N_INT = int(sqrt(3)*2/STEP)-1 = 220 -> 219 samples kept.
//
// NOTE: fp contract OFF — the reference (numpy/jax f32) computes mul-then-add
// with separate roundings; fma contraction shifts g/px by 1 ulp near
// floor(g±0.5) and |p|<1 boundaries, flipping trilinear cells / the mask
// (observed: 1.44e-3 absmax error ~= full-magnitude flips at a few points).

#pragma clang fp contract(off)

#define NRAYS 1024
#define NS    219
#define NPTS  (NRAYS * NS)
#define STEPF 0.015625f   // VOXEL/2 = (2/64)/2, exact power of two

__global__ __launch_bounds__(256) void plenox_sigma_kernel(
    const float* __restrict__ rays_o,
    const float* __restrict__ rays_d,
    const float* __restrict__ grid,
    const float* __restrict__ atoms,
    float* __restrict__ out)
{
#pragma clang fp contract(off)
    // Stage the sigma channel of atoms (8 fine-cells x 32 atoms) into LDS.
    // Row stride 36 floats: rows land on distinct bank groups (fcell*36 mod 32 = fcell*4),
    // and 36*4=144 bytes keeps 16B alignment for float4 reads.
    __shared__ __align__(16) float asig[8 * 36];
    const int t = threadIdx.x;
    {
        const int fcell = t >> 5, a = t & 31;
        asig[fcell * 36 + a] = atoms[t * 13 + 12];
    }
    __syncthreads();

    const int idx = blockIdx.x * 256 + t;
    if (idx >= NPTS) return;
    const int b = idx / NS;
    const int i = idx - b * NS;

    const float ox = rays_o[b * 3 + 0], oy = rays_o[b * 3 + 1], oz = rays_o[b * 3 + 2];
    const float dx = rays_d[b * 3 + 0], dy = rays_d[b * 3 + 1], dz = rays_d[b * 3 + 2];

    // start = max over axes of min((1-o)/d, (-1-o)/d)  (IEEE f32 division, matches numpy)
    const float sx = fminf((1.0f - ox) / dx, (-1.0f - ox) / dx);
    const float sy = fminf((1.0f - oy) / dy, (-1.0f - oy) / dy);
    const float sz = fminf((1.0f - oz) / dz, (-1.0f - oz) / dz);
    const float start = fmaxf(sx, fmaxf(sy, sz));

    // i*STEP is exact (pow2 step, i<=218); one rounded add, same as numpy.
    const float tt = start + (float)i * STEPF;

    // mul then add, separate roundings (contraction disabled above).
    const float px = ox + tt * dx;
    const float py = oy + tt * dy;
    const float pz = oz + tt * dz;

    float sigma = 0.0f;
    if (px > -1.0f && px < 1.0f &&
        py > -1.0f && py < 1.0f &&
        pz > -1.0f && pz < 1.0f) {

        // (p+1)/VOXEL with VOXEL=2^-5: exact scaling either way.
        const float gx = (px + 1.0f) * 32.0f;
        const float gy = (py + 1.0f) * 32.0f;
        const float gz = (pz + 1.0f) * 32.0f;

        int   pX[2], pY[2], pZ[2];
        float wX[2], wY[2], wZ[2];
#pragma unroll
        for (int c = 0; c < 2; ++c) {
            const float off = c ? 0.5f : -0.5f;
            const float fx = fminf(fmaxf(floorf(gx + off), 0.0f), 63.0f);
            const float fy = fminf(fmaxf(floorf(gy + off), 0.0f), 63.0f);
            const float fz = fminf(fmaxf(floorf(gz + off), 0.0f), 63.0f);
            wX[c] = 1.0f - fabsf(gx - (fx + 0.5f));
            wY[c] = 1.0f - fabsf(gy - (fy + 0.5f));
            wZ[c] = 1.0f - fabsf(gz - (fz + 0.5f));
            pX[c] = (int)fx; pY[c] = (int)fy; pZ[c] = (int)fz;
        }

        float acc = 0.0f;
#pragma unroll
        for (int cx = 0; cx < 2; ++cx)
#pragma unroll
        for (int cy = 0; cy < 2; ++cy)
#pragma unroll
        for (int cz = 0; cz < 2; ++cz) {
            const int nx = pX[cx], ny = pY[cy], nz = pZ[cz];
            const int cnx = nx >> 1, cny = ny >> 1, cnz = nz >> 1;
            const int fcell = ((nx & 1) * 2 + (ny & 1)) * 2 + (nz & 1);
            const float4* __restrict__ grow =
                reinterpret_cast<const float4*>(grid + (((cnx * 32) + cny) * 32 + cnz) * 32);
            const float* __restrict__ arow = &asig[fcell * 36];
            const float w3 = wX[cx] * wY[cy] * wZ[cz];   // ((wx*wy)*wz), same as np.prod order
            float dot = 0.0f;
#pragma unroll
            for (int q = 0; q < 8; ++q) {
                const float4 gv = grow[q];
                const float4 av = *reinterpret_cast<const float4*>(arow + q * 4);
                dot += gv.x * av.x + gv.y * av.y + gv.z * av.z + gv.w * av.w;
            }
            acc += w3 * dot;
        }
        sigma = fmaxf(acc, 0.0f);
    }
    out[idx] = sigma;
}

extern "C" void kernel_launch(void* const* d_in, const int* in_sizes, int n_in,
                              void* d_out, int out_size, void* d_ws, size_t ws_size,
                              hipStream_t stream) {
    const float* rays_o = (const float*)d_in[0];
    const float* rays_d = (const float*)d_in[1];
    const float* grid   = (const float*)d_in[2];
    const float* atoms  = (const float*)d_in[3];
    float* out = (float*)d_out;

    const int nblocks = (NPTS + 255) / 256;
    hipLaunchKernelGGL(plenox_sigma_kernel, dim3(nblocks), dim3(256), 0, stream,
                       rays_o, rays_d, grid, atoms, out);
}

// Round 3
// 13.376 us; speedup vs baseline: 1.7594x; 1.7594x over previous
//
#include <hip/hip_runtime.h>

// DictPlenoxels forward, sigma-only, two-stage:
//   Stage 1: D[cell][fcell] = sum_a grid[cell][a] * atoms_sigma[fcell][a]
//            (32768 cells x 8 fine-cells = 1 MB, L2-resident)
//   Stage 2: per sample point, trilinear: sigma = relu(sum_8 w_n * D[cn_n][fn_n])
// This removes the per-point 8x(32-float) grid gather (230 MB of L1 traffic)
// that made R2 L1-throughput-bound at 23.5 us.
//
// fp contract OFF globally: reference (numpy f32) rounds mul and add separately;
// fma contraction flips floor(g+-0.5) / |p|<1 boundaries (R1 failure mode).

#pragma clang fp contract(off)

#define NRAYS 1024
#define NS    219
#define NPTS  (NRAYS * NS)
#define STEPF 0.015625f   // VOXEL/2, exact power of two
#define NCELLS (32 * 32 * 32)
#define D_BYTES (NCELLS * 8 * 4)

// ---------------- Stage 1: fold atoms sigma into grid ----------------
__global__ __launch_bounds__(256) void precompute_D_kernel(
    const float* __restrict__ grid,
    const float* __restrict__ atoms,
    float* __restrict__ D)
{
    __shared__ __align__(16) float asig[256];   // [fcell][atom], fcell = ((fx*2)+fy)*2+fz
    const int t = threadIdx.x;
    asig[t] = atoms[t * 13 + 12];
    __syncthreads();

    const int cell = blockIdx.x * 256 + t;      // 128 blocks x 256 = 32768
    const float4* __restrict__ grow = reinterpret_cast<const float4*>(grid + cell * 32);
    float4 gv[8];
#pragma unroll
    for (int q = 0; q < 8; ++q) gv[q] = grow[q];

    float d[8];
#pragma unroll
    for (int f = 0; f < 8; ++f) {
        float acc = 0.0f;
#pragma unroll
        for (int q = 0; q < 8; ++q) {
            const float4 av = *reinterpret_cast<const float4*>(&asig[f * 32 + q * 4]);
            acc += gv[q].x * av.x + gv[q].y * av.y + gv[q].z * av.z + gv[q].w * av.w;
        }
        d[f] = acc;
    }
    float4* __restrict__ drow = reinterpret_cast<float4*>(D + cell * 8);
    drow[0] = make_float4(d[0], d[1], d[2], d[3]);
    drow[1] = make_float4(d[4], d[5], d[6], d[7]);
}

// ---------------- Stage 2: per-point trilinear over D ----------------
__global__ __launch_bounds__(256) void plenox_sigma_fast(
    const float* __restrict__ rays_o,
    const float* __restrict__ rays_d,
    const float* __restrict__ D,
    float* __restrict__ out)
{
    const int idx = blockIdx.x * 256 + threadIdx.x;
    if (idx >= NPTS) return;
    const int b = idx / NS;
    const int i = idx - b * NS;

    const float ox = rays_o[b * 3 + 0], oy = rays_o[b * 3 + 1], oz = rays_o[b * 3 + 2];
    const float dx = rays_d[b * 3 + 0], dy = rays_d[b * 3 + 1], dz = rays_d[b * 3 + 2];

    const float sx = fminf((1.0f - ox) / dx, (-1.0f - ox) / dx);
    const float sy = fminf((1.0f - oy) / dy, (-1.0f - oy) / dy);
    const float sz = fminf((1.0f - oz) / dz, (-1.0f - oz) / dz);
    const float start = fmaxf(sx, fmaxf(sy, sz));
    const float tt = start + (float)i * STEPF;

    const float px = ox + tt * dx;   // mul then add, separate roundings
    const float py = oy + tt * dy;
    const float pz = oz + tt * dz;

    float sigma = 0.0f;
    if (px > -1.0f && px < 1.0f &&
        py > -1.0f && py < 1.0f &&
        pz > -1.0f && pz < 1.0f) {

        const float gx = (px + 1.0f) * 32.0f;
        const float gy = (py + 1.0f) * 32.0f;
        const float gz = (pz + 1.0f) * 32.0f;

        int   pX[2], pY[2], pZ[2];
        float wX[2], wY[2], wZ[2];
#pragma unroll
        for (int c = 0; c < 2; ++c) {
            const float off = c ? 0.5f : -0.5f;
            const float fx = fminf(fmaxf(floorf(gx + off), 0.0f), 63.0f);
            const float fy = fminf(fmaxf(floorf(gy + off), 0.0f), 63.0f);
            const float fz = fminf(fmaxf(floorf(gz + off), 0.0f), 63.0f);
            wX[c] = 1.0f - fabsf(gx - (fx + 0.5f));
            wY[c] = 1.0f - fabsf(gy - (fy + 0.5f));
            wZ[c] = 1.0f - fabsf(gz - (fz + 0.5f));
            pX[c] = (int)fx; pY[c] = (int)fy; pZ[c] = (int)fz;
        }

        float acc = 0.0f;
#pragma unroll
        for (int cx = 0; cx < 2; ++cx)
#pragma unroll
        for (int cy = 0; cy < 2; ++cy)
#pragma unroll
        for (int cz = 0; cz < 2; ++cz) {
            const int nx = pX[cx], ny = pY[cy], nz = pZ[cz];
            const int cell = (((nx >> 1) * 32) + (ny >> 1)) * 32 + (nz >> 1);
            const int fcell = ((nx & 1) * 2 + (ny & 1)) * 2 + (nz & 1);
            const float w3 = wX[cx] * wY[cy] * wZ[cz];
            acc += w3 * D[cell * 8 + fcell];
        }
        sigma = fmaxf(acc, 0.0f);
    }
    out[idx] = sigma;
}

// ---------------- Fallback (R2, passing): direct gather ----------------
__global__ __launch_bounds__(256) void plenox_sigma_kernel(
    const float* __restrict__ rays_o,
    const float* __restrict__ rays_d,
    const float* __restrict__ grid,
    const float* __restrict__ atoms,
    float* __restrict__ out)
{
    __shared__ __align__(16) float asig[8 * 36];
    const int t = threadIdx.x;
    {
        const int fcell = t >> 5, a = t & 31;
        asig[fcell * 36 + a] = atoms[t * 13 + 12];
    }
    __syncthreads();

    const int idx = blockIdx.x * 256 + t;
    if (idx >= NPTS) return;
    const int b = idx / NS;
    const int i = idx - b * NS;

    const float ox = rays_o[b * 3 + 0], oy = rays_o[b * 3 + 1], oz = rays_o[b * 3 + 2];
    const float dx = rays_d[b * 3 + 0], dy = rays_d[b * 3 + 1], dz = rays_d[b * 3 + 2];

    const float sx = fminf((1.0f - ox) / dx, (-1.0f - ox) / dx);
    const float sy = fminf((1.0f - oy) / dy, (-1.0f - oy) / dy);
    const float sz = fminf((1.0f - oz) / dz, (-1.0f - oz) / dz);
    const float start = fmaxf(sx, fmaxf(sy, sz));
    const float tt = start + (float)i * STEPF;

    const float px = ox + tt * dx;
    const float py = oy + tt * dy;
    const float pz = oz + tt * dz;

    float sigma = 0.0f;
    if (px > -1.0f && px < 1.0f &&
        py > -1.0f && py < 1.0f &&
        pz > -1.0f && pz < 1.0f) {

        const float gx = (px + 1.0f) * 32.0f;
        const float gy = (py + 1.0f) * 32.0f;
        const float gz = (pz + 1.0f) * 32.0f;

        int   pX[2], pY[2], pZ[2];
        float wX[2], wY[2], wZ[2];
#pragma unroll
        for (int c = 0; c < 2; ++c) {
            const float off = c ? 0.5f : -0.5f;
            const float fx = fminf(fmaxf(floorf(gx + off), 0.0f), 63.0f);
            const float fy = fminf(fmaxf(floorf(gy + off), 0.0f), 63.0f);
            const float fz = fminf(fmaxf(floorf(gz + off), 0.0f), 63.0f);
            wX[c] = 1.0f - fabsf(gx - (fx + 0.5f));
            wY[c] = 1.0f - fabsf(gy - (fy + 0.5f));
            wZ[c] = 1.0f - fabsf(gz - (fz + 0.5f));
            pX[c] = (int)fx; pY[c] = (int)fy; pZ[c] = (int)fz;
        }

        float acc = 0.0f;
#pragma unroll
        for (int cx = 0; cx < 2; ++cx)
#pragma unroll
        for (int cy = 0; cy < 2; ++cy)
#pragma unroll
        for (int cz = 0; cz < 2; ++cz) {
            const int nx = pX[cx], ny = pY[cy], nz = pZ[cz];
            const int cnx = nx >> 1, cny = ny >> 1, cnz = nz >> 1;
            const int fcell = ((nx & 1) * 2 + (ny & 1)) * 2 + (nz & 1);
            const float4* __restrict__ grow =
                reinterpret_cast<const float4*>(grid + (((cnx * 32) + cny) * 32 + cnz) * 32);
            const float* __restrict__ arow = &asig[fcell * 36];
            const float w3 = wX[cx] * wY[cy] * wZ[cz];
            float dot = 0.0f;
#pragma unroll
            for (int q = 0; q < 8; ++q) {
                const float4 gv = grow[q];
                const float4 av = *reinterpret_cast<const float4*>(arow + q * 4);
                dot += gv.x * av.x + gv.y * av.y + gv.z * av.z + gv.w * av.w;
            }
            acc += w3 * dot;
        }
        sigma = fmaxf(acc, 0.0f);
    }
    out[idx] = sigma;
}

extern "C" void kernel_launch(void* const* d_in, const int* in_sizes, int n_in,
                              void* d_out, int out_size, void* d_ws, size_t ws_size,
                              hipStream_t stream) {
    const float* rays_o = (const float*)d_in[0];
    const float* rays_d = (const float*)d_in[1];
    const float* grid   = (const float*)d_in[2];
    const float* atoms  = (const float*)d_in[3];
    float* out = (float*)d_out;

    const int nblocks = (NPTS + 255) / 256;

    if (ws_size >= (size_t)D_BYTES) {
        float* D = (float*)d_ws;
        hipLaunchKernelGGL(precompute_D_kernel, dim3(NCELLS / 256), dim3(256), 0, stream,
                           grid, atoms, D);
        hipLaunchKernelGGL(plenox_sigma_fast, dim3(nblocks), dim3(256), 0, stream,
                           rays_o, rays_d, D, out);
    } else {
        hipLaunchKernelGGL(plenox_sigma_kernel, dim3(nblocks), dim3(256), 0, stream,
                           rays_o, rays_d, grid, atoms, out);
    }
}